// Round 1
// baseline (1016.685 us; speedup 1.0000x reference)
//
#include <hip/hip_runtime.h>
#include <math.h>

#define BB 32
#define TT 50
#define CC 501
#define NNODES (BB*CC)          // 16032
#define GPB 32                  // node-groups (nodes) per block
#define NTHREADS (GPB*32)       // 1024
#define NBLK (NNODES/GPB)       // 501
#define BN_SCALEF 0.9999950000374996f

// workspace layout (floats)
#define HT_SZ   (NNODES*32)     // 513024
#define P_SZ    (CC*32)         // 16032
#define GT_SZ   (CC*CC)         // 251001
#define PERB_BUF (BB*96)        // 3072 per buffer, double buffered

__device__ __forceinline__ float dot4(float4 a, float4 b){
    return a.x*b.x + a.y*b.y + a.z*b.z + a.w*b.w;
}
__device__ __forceinline__ float sigm(float x){ return 1.f/(1.f+__expf(-x)); }
__device__ __forceinline__ float tanhfast(float x){ return 1.f - 2.f/(__expf(2.f*x)+1.f); }

// ---------------- init: zero ht + transpose graph ----------------
__global__ void init0_kernel(const float* __restrict__ graph,
                             float* __restrict__ graphT,
                             float* __restrict__ ht) {
    int i = blockIdx.x*blockDim.x + threadIdx.x;
    if (i < HT_SZ) ht[i] = 0.f;
    if (i < GT_SZ) {
        int r = i / CC, c2 = i % CC;       // graphT[r][c2] = graph[c2][r]
        graphT[i] = graph[c2*CC + r];
    }
}

// ---------------- init: P0/P1 (per-concept const part of layer1) ----------------
__global__ void pk_kernel(const float* __restrict__ n0_w1, const float* __restrict__ n1_w1,
                          const float* __restrict__ emb_c,
                          float* __restrict__ P0, float* __restrict__ P1) {
    int c = blockIdx.x;
    int which = threadIdx.x >> 5, j = threadIdx.x & 31;
    float ec = emb_c[c*32 + j];
    const float* W = which ? n1_w1 : n0_w1;
    float acc = 0.f;
    #pragma unroll
    for (int k = 0; k < 32; k++)
        acc += W[j*128 + 96 + k] * __shfl(ec, k, 32);
    (which ? P1 : P0)[c*32 + j] = acc;
}

// ---------------- init: per-b quantities for step 0 (h_q = 0) ----------------
__global__ void perb0_kernel(const int* __restrict__ features, const float* __restrict__ emb_x,
                             const float* __restrict__ n0_w1, const float* __restrict__ n0_b1,
                             const float* __restrict__ n1_w1, const float* __restrict__ n1_b1,
                             const float* __restrict__ self_w1, const float* __restrict__ self_b1,
                             const float* __restrict__ self_w2, const float* __restrict__ self_b2,
                             float* __restrict__ perb) {
    int b = threadIdx.x >> 5, j = threadIdx.x & 31;
    int xt = features[b*TT + 0];
    float eq = emb_x[xt*32 + j];
    float a0 = n0_b1[j], a1 = n1_b1[j], s = self_b1[j];
    #pragma unroll
    for (int k = 0; k < 32; k++) {
        float ek = __shfl(eq, k, 32);
        a0 += n0_w1[j*128 + 32 + k] * ek;
        a1 += n1_w1[j*128 + 32 + k] * ek;
        s  += self_w1[j*64 + 32 + k] * ek;
    }
    float l1 = fmaxf(s, 0.f);
    float s2 = self_b2[j];
    #pragma unroll
    for (int k = 0; k < 32; k++) s2 += self_w2[j*32 + k] * __shfl(l1, k, 32);
    perb[b*96 + j]      = a0;
    perb[b*96 + 32 + j] = a1;
    perb[b*96 + 64 + j] = fmaxf(s2, 0.f) * BN_SCALEF;
}

// ---------------- one recurrence step ----------------
__global__ __launch_bounds__(NTHREADS) void step_kernel(
    int t,
    const int* __restrict__ features, const int* __restrict__ questions,
    const float* __restrict__ graph,  const float* __restrict__ emb_x,
    const float* __restrict__ self_w1, const float* __restrict__ self_b1,
    const float* __restrict__ self_w2, const float* __restrict__ self_b2,
    const float* __restrict__ n0_w1, const float* __restrict__ n0_b1,
    const float* __restrict__ n0_w2, const float* __restrict__ n0_b2,
    const float* __restrict__ n1_w1, const float* __restrict__ n1_b1,
    const float* __restrict__ n1_w2, const float* __restrict__ n1_b2,
    const float* __restrict__ ea_w,  const float* __restrict__ ea_ew,
    const float* __restrict__ ea_eb, const float* __restrict__ ea_aw,
    const float* __restrict__ ea_ab,
    const float* __restrict__ gru_w_ih, const float* __restrict__ gru_w_hh,
    const float* __restrict__ gru_b_ih, const float* __restrict__ gru_b_hh,
    const float* __restrict__ pred_w,   const float* __restrict__ pred_b,
    float* __restrict__ ht,
    const float* __restrict__ P0, const float* __restrict__ P1,
    const float* __restrict__ graphT,
    float* __restrict__ perb, float* __restrict__ out)
{
    // LDS: weights, chunked-transposed so lane j does conflict-free ds_read_b128:
    //  [0,1024)   Ch0  (n0_w1 cols 64:96)   layout [kc][j][4]
    //  [1024,2048) Ch1
    //  [2048,3072) W20 (n0_w2)
    //  [3072,4096) W21
    //  [4096,5120) EW  (ea_ew)
    //  [5120,6144) AW  (ea_aw)
    //  [6144,9216) Wih (96 rows) layout [kc][row][4]
    //  [9216,12288) Whh
    __shared__ float Wq[12288];
    __shared__ float bufH[GPB][36];   // pad 36: bank (4g+k)%32, groups g/g+1 disjoint
    __shared__ float bufA[GPB][36];
    __shared__ float bufB[GPB][36];

    int tid = threadIdx.x;
    for (int idx = tid; idx < 12288; idx += NTHREADS) {
        float v;
        if (idx < 6144) {
            int region = idx >> 10;
            int r = idx & 1023;
            int j = (r >> 2) & 31;
            int k = ((r >> 7) << 2) | (r & 3);
            switch (region) {
                case 0:  v = n0_w1[j*128 + 64 + k]; break;
                case 1:  v = n1_w1[j*128 + 64 + k]; break;
                case 2:  v = n0_w2[j*32 + k]; break;
                case 3:  v = n1_w2[j*32 + k]; break;
                case 4:  v = ea_ew[j*32 + k]; break;
                default: v = ea_aw[j*32 + k]; break;
            }
            Wq[idx] = v;
        } else {
            int r = idx - 6144;
            int which = r / 3072;
            int r2 = r % 3072;
            int row = (r2 >> 2) % 96;
            int k = ((r2 / 384) << 2) | (r2 & 3);
            Wq[idx] = which ? gru_w_hh[row*32 + k] : gru_w_ih[row*32 + k];
        }
    }

    int g = tid >> 5, j = tid & 31;
    int node = blockIdx.x * GPB + g;          // exact: 501*32 = 16032
    int b = node / CC, c = node % CC;
    int qt = questions[b*TT + t];
    float adj  = graph [qt*CC + c];
    float radj = graphT[qt*CC + c];
    float h_j = ht[node*32 + j];
    bufH[g][j] = h_j;
    __syncthreads();   // weights + bufH visible

    const float* pb = perb + (t & 1) * PERB_BUF + b*96;

    // ---- phase 1: t0/t1 = relu(perb + P + Ch@h) ----
    float acc0 = pb[j]      + P0[c*32 + j];
    float acc1 = pb[32 + j] + P1[c*32 + j];
    {
        const float4* xh = (const float4*)bufH[g];
        #pragma unroll
        for (int kc = 0; kc < 8; kc++) {
            float4 x  = xh[kc];
            float4 w0 = *(const float4*)&Wq[       kc*128 + j*4];
            float4 w1 = *(const float4*)&Wq[1024 + kc*128 + j*4];
            acc0 += dot4(w0, x);
            acc1 += dot4(w1, x);
        }
    }
    bufA[g][j] = fmaxf(acc0, 0.f);
    bufB[g][j] = fmaxf(acc1, 0.f);

    // ---- phase 2: f0/f1 = relu(W2@t)*BN; m = adj*f0 + radj*f1 ----
    float a0 = n0_b2[j], a1 = n1_b2[j];
    {
        const float4* xa = (const float4*)bufA[g];
        const float4* xb = (const float4*)bufB[g];
        #pragma unroll
        for (int kc = 0; kc < 8; kc++) {
            float4 va = xa[kc], vb = xb[kc];
            float4 w0 = *(const float4*)&Wq[2048 + kc*128 + j*4];
            float4 w1 = *(const float4*)&Wq[3072 + kc*128 + j*4];
            a0 += dot4(w0, va);
            a1 += dot4(w1, vb);
        }
    }
    float f0 = fmaxf(a0, 0.f) * BN_SCALEF;
    float f1 = fmaxf(a1, 0.f) * BN_SCALEF;
    float m = adj*f0 + radj*f1;
    if (c == qt) m = pb[64 + j];              // self_feat overwrite
    bufA[g][j] = m;                            // group-local, wave-ordered

    // ---- phase 3: edge attention ----
    float e = ea_eb[j], aa = ea_ab[j];
    {
        const float4* xm = (const float4*)bufA[g];
        #pragma unroll
        for (int kc = 0; kc < 8; kc++) {
            float4 vm = xm[kc];
            float4 we = *(const float4*)&Wq[4096 + kc*128 + j*4];
            float4 wa = *(const float4*)&Wq[5120 + kc*128 + j*4];
            e  += dot4(we, vm);
            aa += dot4(wa, vm);
        }
    }
    float eg = sigm(e);
    float af = tanhfast(aa);
    float wc = ea_w[c];
    float mm = m - wc*eg*m + wc*af;
    bufB[g][j] = mm;                           // group-local, wave-ordered

    // ---- phase 4: GRU ----
    float g0 = gru_b_ih[j], g1 = gru_b_ih[32+j], g2 = gru_b_ih[64+j];
    float hh0 = gru_b_hh[j], hh1 = gru_b_hh[32+j], hh2 = gru_b_hh[64+j];
    {
        const float4* xm = (const float4*)bufB[g];
        const float4* xh = (const float4*)bufH[g];
        #pragma unroll
        for (int kc = 0; kc < 8; kc++) {
            float4 vm = xm[kc], vh = xh[kc];
            const float* wi = &Wq[6144 + kc*384];
            const float* wh = &Wq[9216 + kc*384];
            float4 wi0 = *(const float4*)&wi[j*4];
            float4 wi1 = *(const float4*)&wi[(32+j)*4];
            float4 wi2 = *(const float4*)&wi[(64+j)*4];
            float4 wh0 = *(const float4*)&wh[j*4];
            float4 wh1 = *(const float4*)&wh[(32+j)*4];
            float4 wh2 = *(const float4*)&wh[(64+j)*4];
            g0  += dot4(wi0, vm);  g1  += dot4(wi1, vm);  g2  += dot4(wi2, vm);
            hh0 += dot4(wh0, vh);  hh1 += dot4(wh1, vh);  hh2 += dot4(wh2, vh);
        }
    }
    float r = sigm(g0 + hh0);
    float z = sigm(g1 + hh1);
    float n = tanhfast(g2 + r*hh2);
    float hn = (1.f - z)*n + z*h_j;
    ht[node*32 + j] = hn;

    // ---- phase 5: prediction for (b, q_{t+1}) + per-b prep for step t+1 ----
    int qn = questions[b*TT + t + 1];          // t <= 48, so valid
    if (c == qn) {
        float v = hn * pred_w[j];
        #pragma unroll
        for (int off = 16; off; off >>= 1) v += __shfl_down(v, off, 32);
        if (j == 0) out[b*(TT-1) + t] = sigm(v + pred_b[0]);

        if (t < TT - 2) {                      // prepare perb for step t+1
            int xt1 = features[b*TT + t + 1];
            float eq = emb_x[xt1*32 + j];
            float accA0 = n0_b1[j], accA1 = n1_b1[j], accS = self_b1[j];
            #pragma unroll
            for (int k = 0; k < 32; k++) {
                float hk = __shfl(hn, k, 32);
                float ek = __shfl(eq, k, 32);
                accA0 += n0_w1[j*128 + k]*hk + n0_w1[j*128 + 32 + k]*ek;
                accA1 += n1_w1[j*128 + k]*hk + n1_w1[j*128 + 32 + k]*ek;
                accS  += self_w1[j*64 + k]*hk + self_w1[j*64 + 32 + k]*ek;
            }
            float l1 = fmaxf(accS, 0.f);
            float s2 = self_b2[j];
            #pragma unroll
            for (int k = 0; k < 32; k++) s2 += self_w2[j*32 + k] * __shfl(l1, k, 32);
            float* pn = perb + ((t+1) & 1) * PERB_BUF + b*96;
            pn[j]      = accA0;
            pn[32 + j] = accA1;
            pn[64 + j] = fmaxf(s2, 0.f) * BN_SCALEF;
        }
    }
}

extern "C" void kernel_launch(void* const* d_in, const int* in_sizes, int n_in,
                              void* d_out, int out_size, void* d_ws, size_t ws_size,
                              hipStream_t stream) {
    const int*   features = (const int*)  d_in[0];
    const int*   questions= (const int*)  d_in[1];
    const float* graph    = (const float*)d_in[2];
    const float* emb_x    = (const float*)d_in[3];
    const float* emb_c    = (const float*)d_in[4];
    const float* self_w1  = (const float*)d_in[5];
    const float* self_b1  = (const float*)d_in[6];
    const float* self_w2  = (const float*)d_in[7];
    const float* self_b2  = (const float*)d_in[8];
    const float* n0_w1    = (const float*)d_in[9];
    const float* n0_b1    = (const float*)d_in[10];
    const float* n0_w2    = (const float*)d_in[11];
    const float* n0_b2    = (const float*)d_in[12];
    const float* n1_w1    = (const float*)d_in[13];
    const float* n1_b1    = (const float*)d_in[14];
    const float* n1_w2    = (const float*)d_in[15];
    const float* n1_b2    = (const float*)d_in[16];
    const float* ea_w     = (const float*)d_in[17];
    const float* ea_ew    = (const float*)d_in[18];
    const float* ea_eb    = (const float*)d_in[19];
    const float* ea_aw    = (const float*)d_in[20];
    const float* ea_ab    = (const float*)d_in[21];
    const float* gru_w_ih = (const float*)d_in[22];
    const float* gru_w_hh = (const float*)d_in[23];
    const float* gru_b_ih = (const float*)d_in[24];
    const float* gru_b_hh = (const float*)d_in[25];
    const float* pred_w   = (const float*)d_in[26];
    const float* pred_b   = (const float*)d_in[27];
    float* out = (float*)d_out;

    float* ws     = (float*)d_ws;
    float* ht     = ws;
    float* P0     = ht + HT_SZ;
    float* P1     = P0 + P_SZ;
    float* graphT = P1 + P_SZ;
    float* perb   = graphT + GT_SZ;

    init0_kernel<<<(HT_SZ + 255)/256, 256, 0, stream>>>(graph, graphT, ht);
    pk_kernel<<<CC, 64, 0, stream>>>(n0_w1, n1_w1, emb_c, P0, P1);
    perb0_kernel<<<1, NTHREADS, 0, stream>>>(features, emb_x,
        n0_w1, n0_b1, n1_w1, n1_b1, self_w1, self_b1, self_w2, self_b2, perb);

    for (int t = 0; t < TT - 1; t++) {
        step_kernel<<<NBLK, NTHREADS, 0, stream>>>(
            t, features, questions, graph, emb_x,
            self_w1, self_b1, self_w2, self_b2,
            n0_w1, n0_b1, n0_w2, n0_b2,
            n1_w1, n1_b1, n1_w2, n1_b2,
            ea_w, ea_ew, ea_eb, ea_aw, ea_ab,
            gru_w_ih, gru_w_hh, gru_b_ih, gru_b_hh,
            pred_w, pred_b,
            ht, P0, P1, graphT, perb, out);
    }
}